// Round 11
// baseline (162.183 us; speedup 1.0000x reference)
//
#include <hip/hip_runtime.h>
#include <hip/hip_bf16.h>
#include <math.h>

#define B_ROWS 16384
#define C_COLS 1000
#define C_PAD  1024
#define FDIM   1024
#define FBLKS  4096           // feature normalize blocks (4 rows each)
#define FP8_SCALE 256.0f      // pre-scale before e4m3 quant (avoids subnormals)
#define INV_SIM   (1.0f / (FP8_SCALE * FP8_SCALE))

typedef __attribute__((ext_vector_type(8))) short bf16x8;
typedef __attribute__((ext_vector_type(4))) float f32x4;
typedef __attribute__((ext_vector_type(4))) int   i32x4;
typedef __attribute__((ext_vector_type(8))) int   i32x8;

// async global->LDS, 16B per lane; lds dst is wave-uniform base (HW puts lane i at base + i*16)
#define GLD_LDS(gp, lp) __builtin_amdgcn_global_load_lds( \
    (__attribute__((address_space(1))) void*)(gp),        \
    (__attribute__((address_space(3))) void*)(lp), 16, 0, 0)

// ---------------- fused row L2-normalize fp32 -> fp8 e4m3 (x256), one wave per row ---------
__global__ __launch_bounds__(256) void normalize_all(
    const float* __restrict__ feat, const float* __restrict__ prot,
    unsigned char* __restrict__ fb, unsigned char* __restrict__ pb,
    float* __restrict__ rowsum)
{
    const int lane = threadIdx.x & 63;
    const int wave = threadIdx.x >> 6;

    // fold rowsum zeroing into the first 64 blocks (replaces the memset dispatch)
    if (blockIdx.x < 64) rowsum[blockIdx.x * 256 + threadIdx.x] = 0.0f;

    const float* in;
    unsigned char* out;
    int row, nvalid;
    if (blockIdx.x < FBLKS) {
        row = blockIdx.x * 4 + wave;  in = feat; out = fb; nvalid = B_ROWS;
    } else {
        row = (blockIdx.x - FBLKS) * 4 + wave;  in = prot; out = pb; nvalid = C_COLS;
    }
    unsigned char* orow = out + (size_t)row * FDIM;

    if (row >= nvalid) {               // zero-pad prototype rows 1000..1023
        i32x4 z = {0, 0, 0, 0};
        ((i32x4*)orow)[lane] = z;      // 64 lanes x 16 B = 1024 B row
        return;
    }

    // lane owns 16 contiguous elements -> one 16 B fp8 store
    const float4* rp = (const float4*)(in + (size_t)row * FDIM);
    float4 v[4];
    float ss = 0.0f;
    #pragma unroll
    for (int c = 0; c < 4; ++c) {
        v[c] = rp[lane * 4 + c];
        ss += v[c].x * v[c].x + v[c].y * v[c].y + v[c].z * v[c].z + v[c].w * v[c].w;
    }
    #pragma unroll
    for (int off = 1; off < 64; off <<= 1) ss += __shfl_xor(ss, off, 64);
    const float inv = FP8_SCALE / sqrtf(fmaxf(ss, 1e-24f));

    i32x4 pk;
    #pragma unroll
    for (int c = 0; c < 4; ++c) {
        int w0 = __builtin_amdgcn_cvt_pk_fp8_f32(v[c].x * inv, v[c].y * inv, 0, false);
        w0     = __builtin_amdgcn_cvt_pk_fp8_f32(v[c].z * inv, v[c].w * inv, w0, true);
        pk[c] = w0;
    }
    ((i32x4*)orow)[lane] = pk;
}

// ---------------- MX-fp8 GEMM 256x256, BK=128, 4-phase interleave + counted vmcnt ---------
// r11 change vs r10: the per-K-tile 32-MFMA monolith is split into 4 PHASES (m201 pattern):
//   { ds_read 4-12 x b128 ; [lgkmcnt(8)] ; s_barrier ; lgkmcnt(0) ; setprio(1) ;
//     8 MFMA (2 mt x 4 nt, independent accs -> pipelined issue) ; setprio(0) ; s_barrier }
// The 8 MFMAs ISSUE in ~60cy and retire in the matrix pipe in background; the trailing
// barrier releases on issue, so the next phase's LDS reads overlap the previous phase's
// matrix-pipe execution (m196: this fine interleave is the lever, +28-41%).
// Staging unchanged from the proven r6/r10 schedule: burst of 8 GLDs per K-tile at tile
// end (all reads landed by P3's lgkmcnt(0)+barrier), validated by entry vmcnt(8)
// (vmcnt(0) for the last tile -- only 8 GLDs outstanding there). A-frags now read
// 2-mt-at-a-time -> register peak ~200 (< 256 @ 2 waves/SIMD).
__global__ __launch_bounds__(512, 2) void gemm_dist(
    const unsigned char* __restrict__ A,
    const unsigned char* __restrict__ Bp,
    __hip_bfloat16* __restrict__ D,
    float* __restrict__ rowsum)
{
    extern __shared__ unsigned char LDS[];        // 131072 B: A dbuf [0,64K), B dbuf [64K,128K)
    unsigned char* As = LDS;                      // + buf*32768
    unsigned char* Bs = LDS + 65536;

    const int tid  = threadIdx.x;                 // 0..511
    const int lane = tid & 63;
    const int wave = tid >> 6;                    // 0..7

    // XCD swizzle: 256 blocks, 8 XCDs; the 4 bn-blocks of one bm share xcd
    const int id  = blockIdx.x;             // 0..255
    const int xcd = id & 7;
    const int seq = id >> 3;                // 0..31
    const int bn  = seq & 3;                // 0..3
    const int bm  = xcd * 8 + (seq >> 2);   // 0..63

    const int waveM = (wave >> 2) * 128;    // 0 / 128
    const int waveN = (wave & 3) * 64;      // 0..192

    f32x4 acc[8][4] = {};

    // staging: wave w owns rows [w*32, w*32+32) of both tiles; round r -> rows w*32+r*8..+8
    // lane i -> row +(i>>3), phys granule i&7, fetching logical granule (i&7)^(i>>3)
    const int srow8 = lane >> 3;
    const int sg    = (lane & 7) ^ srow8;
    const unsigned char* Abase = A  + ((size_t)(bm * 256 + wave * 32 + srow8)) * FDIM + sg * 16;
    const unsigned char* Bbase = Bp + ((size_t)(bn * 256 + wave * 32 + srow8)) * FDIM + sg * 16;
    const int ldsW = wave * 4096;           // wave's 32-row strip (32*128 B) within a tile

    // frag addressing: R = waveX + mt*16 + (lane&15); R&7 = lane&7.
    // logical granules for this lane: 2q, 2q+1 (q = lane>>4); phys = g ^ (lane&7)
    const int q2   = (lane >> 4) * 2;
    const int bxor = lane & 7;
    const int fA = (waveM + (lane & 15)) * 128;
    const int fB = (waveN + (lane & 15)) * 128;
    const int pg0 = ((q2)     ^ bxor) * 16;
    const int pg1 = ((q2 + 1) ^ bxor) * 16;

    // batch issue: 4 A-rounds + 4 B-rounds = 8 GLDs/wave (the vmcnt unit)
#define STAGE_BATCH(K0_, BUF_) do {                                                  \
        _Pragma("unroll")                                                            \
        for (int r_ = 0; r_ < 4; ++r_)                                               \
            GLD_LDS(Abase + (size_t)(r_ * 8) * FDIM + (K0_), &As[(BUF_) + ldsW + r_ * 1024]); \
        _Pragma("unroll")                                                            \
        for (int r_ = 0; r_ < 4; ++r_)                                               \
            GLD_LDS(Bbase + (size_t)(r_ * 8) * FDIM + (K0_), &Bs[(BUF_) + ldsW + r_ * 1024]); \
    } while (0)

    // prologue: batch0 -> buf0, batch1 -> buf1 (issue order = vmcnt retirement order)
    STAGE_BATCH(0, 0);
    __builtin_amdgcn_sched_barrier(0);
    STAGE_BATCH(128, 32768);
    __builtin_amdgcn_sched_barrier(0);

    #pragma unroll 1
    for (int t = 0; t < 8; ++t) {
        const int cur = (t & 1) << 15;      // byte offset of current buffer (0 / 32768)

        // validate buf[cur]: retire burst t. Outstanding at entry: bursts {t, t+1} -> 16
        // GLDs -> vmcnt(8). Last tile: only burst 7 outstanding (8 GLDs) -> vmcnt(0).
        if (t < 7) { asm volatile("s_waitcnt vmcnt(8)" ::: "memory"); }
        else       { asm volatile("s_waitcnt vmcnt(0)" ::: "memory"); }
        __builtin_amdgcn_s_barrier();
        __builtin_amdgcn_sched_barrier(0);

        i32x8 b4[4];                        // B frags live across all 4 phases
        #pragma unroll
        for (int p = 0; p < 4; ++p) {
            // phase p ds-load: B (8 reads, phase 0 only) + A for mt = 2p, 2p+1 (4 reads)
            if (p == 0) {
                #pragma unroll
                for (int nt = 0; nt < 4; ++nt) {
                    ((i32x4*)&b4[nt])[0] = *(const i32x4*)&Bs[cur + fB + nt * 2048 + pg0];
                    ((i32x4*)&b4[nt])[1] = *(const i32x4*)&Bs[cur + fB + nt * 2048 + pg1];
                }
            }
            i32x8 a2[2];
            #pragma unroll
            for (int m2 = 0; m2 < 2; ++m2) {
                const int mt = p * 2 + m2;
                ((i32x4*)&a2[m2])[0] = *(const i32x4*)&As[cur + fA + mt * 2048 + pg0];
                ((i32x4*)&a2[m2])[1] = *(const i32x4*)&As[cur + fA + mt * 2048 + pg1];
            }
            if (p == 0) { asm volatile("s_waitcnt lgkmcnt(8)" ::: "memory"); }  // 12 reads issued
            __builtin_amdgcn_s_barrier();
            asm volatile("s_waitcnt lgkmcnt(0)" ::: "memory");
            __builtin_amdgcn_sched_barrier(0);
            __builtin_amdgcn_s_setprio(1);
            #pragma unroll
            for (int m2 = 0; m2 < 2; ++m2)
                #pragma unroll
                for (int nt = 0; nt < 4; ++nt)
                    acc[p * 2 + m2][nt] = __builtin_amdgcn_mfma_scale_f32_16x16x128_f8f6f4(
                        a2[m2], b4[nt], acc[p * 2 + m2][nt], 0, 0, 0, 127, 0, 127);
            __builtin_amdgcn_s_setprio(0);
            __builtin_amdgcn_s_barrier();
            __builtin_amdgcn_sched_barrier(0);
        }

        // end of tile: every wave did lgkmcnt(0) before its P3 MFMAs and passed the
        // trailing barrier -> all reads of buf[cur] landed -> safe to overwrite with
        // burst t+2. Those loads stay in flight across the next tiles (counted vmcnt).
        if (t < 6) {
            STAGE_BATCH((t + 2) * 128, cur);
            __builtin_amdgcn_sched_barrier(0);
        }
    }

    // epilogue: sim = acc/65536; d = sqrt(max(1-sim,0)); C/D: col=lane&15, row=(lane>>4)*4+reg
    const int row0 = bm * 256 + waveM;
    const int col0 = bn * 256 + waveN;
    #pragma unroll
    for (int mt = 0; mt < 8; ++mt) {
        #pragma unroll
        for (int r = 0; r < 4; ++r) {
            const int row = row0 + mt * 16 + (lane >> 4) * 4 + r;
            float part = 0.0f;
            #pragma unroll
            for (int nt = 0; nt < 4; ++nt) {
                const int col = col0 + nt * 16 + (lane & 15);
                const float sim = acc[mt][nt][r] * INV_SIM;
                const float dv = sqrtf(fmaxf(1.0f - sim, 0.0f));
                if (col < C_COLS) {
                    D[(size_t)row * C_COLS + col] = __float2bfloat16(dv);
                    part += dv;
                }
            }
            part += __shfl_xor(part, 1, 64);
            part += __shfl_xor(part, 2, 64);
            part += __shfl_xor(part, 4, 64);
            part += __shfl_xor(part, 8, 64);
            if ((lane & 15) == 0) atomicAdd(&rowsum[row], part);
        }
    }
}

// ---------------- finalize: out = (-|ds|/T) * (d + rowsum/1000) ----------------
__global__ __launch_bounds__(256) void finalize(
    const __hip_bfloat16* __restrict__ D, const float* __restrict__ rowsum,
    const float* __restrict__ scale, const float* __restrict__ temp,
    float* __restrict__ out)
{
    const size_t i = (size_t)blockIdx.x * 256 + threadIdx.x;   // 8-element group
    const float a = -fabsf(scale[0]) / temp[0];
    const int row = (int)((i * 8) / C_COLS);                   // 1000 % 8 == 0, no straddle
    const float m = rowsum[row] * (1.0f / (float)C_COLS);

    const bf16x8 dv = *(const bf16x8*)(D + i * 8);
    const __hip_bfloat16* dp = (const __hip_bfloat16*)&dv;
    float4 o0, o1;
    o0.x = a * (__bfloat162float(dp[0]) + m);
    o0.y = a * (__bfloat162float(dp[1]) + m);
    o0.z = a * (__bfloat162float(dp[2]) + m);
    o0.w = a * (__bfloat162float(dp[3]) + m);
    o1.x = a * (__bfloat162float(dp[4]) + m);
    o1.y = a * (__bfloat162float(dp[5]) + m);
    o1.z = a * (__bfloat162float(dp[6]) + m);
    o1.w = a * (__bfloat162float(dp[7]) + m);
    ((float4*)out)[i * 2]     = o0;
    ((float4*)out)[i * 2 + 1] = o1;
}

extern "C" void kernel_launch(void* const* d_in, const int* in_sizes, int n_in,
                              void* d_out, int out_size, void* d_ws, size_t ws_size,
                              hipStream_t stream)
{
    const float* features = (const float*)d_in[0];   // [16384,1024]
    const float* protos   = (const float*)d_in[1];   // [1000,1024]
    const float* dscale   = (const float*)d_in[2];   // [1]
    const float* temp     = (const float*)d_in[3];   // [1]
    float* out = (float*)d_out;                      // [16384,1000]

    char* ws = (char*)d_ws;
    unsigned char* fb = (unsigned char*)ws;                       // 16,777,216 B
    unsigned char* pb = (unsigned char*)(ws + 16777216);          //  1,048,576 B
    __hip_bfloat16* D = (__hip_bfloat16*)(ws + 17825792);         // 32,768,000 B
    float* rowsum     = (float*)(ws + 50593792);                  //     65,536 B

    // one-time: allow 128 KB dynamic LDS for the 256^2 tile (host-side, capture-safe)
    static int lds_ok = 0;
    if (!lds_ok) {
        (void)hipFuncSetAttribute(reinterpret_cast<const void*>(gemm_dist),
                                  hipFuncAttributeMaxDynamicSharedMemorySize, 131072);
        lds_ok = 1;
    }

    normalize_all<<<FBLKS + C_PAD / 4, 256, 0, stream>>>(features, protos, fb, pb, rowsum);

    gemm_dist<<<256, 512, 131072, stream>>>(fb, pb, D, rowsum);

    finalize<<<(B_ROWS * C_COLS / 8) / 256, 256, 0, stream>>>(D, rowsum, dscale, temp, out);
}